// Round 7
// baseline (5701.250 us; speedup 1.0000x reference)
//
#include <hip/hip_runtime.h>
#include <hip/hip_cooperative_groups.h>

// LSTM: B=64, T=256, IN=512, H=1024 (4H=4096), OUT=512. I/O f32.
// Round-17 = r12 VERBATIM (two-plane h layout, flag barrier + acquire
// fence, sc0sc1 h stores — all proven, 4237us) + ONE change: deep
// register prefetch of the gate h stream.
//   r15/r16 post-mortem: both failed with the BIT-IDENTICAL absmax
//   (1.0703125) though r16 restored the fence -> not a coherence bug;
//   shared deltas were (interleaved h layout) + (prefetch). This round
//   bisects: r12 layout kept verbatim, ONLY the prefetch added.
//   Hazard guarded: __syncthreads is workgroup-scope only — LLVM may
//   hoist GLOBAL loads above it; a loop-top asm memory barrier pins
//   the prefetch below the grid barrier.
// Accumulation order identical to r12 (x 0..15, then h 0..31 in the
// same per-chain order) -> bitwise-identical numerics (absmax 7.8e-3).

#define B_   64
#define T_   256
#define IN_  512
#define H_   1024
#define G4_  4096
#define OUT_ 512
#define KTOT 1536   // IN_ + H_

typedef __bf16 bf8v  __attribute__((ext_vector_type(8)));
typedef float  f4v   __attribute__((ext_vector_type(4)));

__device__ __forceinline__ float sigm(float x) { return 1.f / (1.f + __expf(-x)); }
__device__ __forceinline__ float tanh_f(float x) { return 1.f - 2.f / (__expf(2.f * x) + 1.f); }

__device__ __forceinline__ bf8v load16(const __bf16* p) {
    f4v t = *(const f4v*)p;
    return __builtin_bit_cast(bf8v, t);
}

// Write-through store of one bf16, bypassing L1 (sc0) and L2 (sc1):
// value is visible at the LLC (agent coherence point) when vmcnt retires.
__device__ __forceinline__ void store_bf16_wt(__bf16* p, __bf16 v) {
    union { __bf16 b; unsigned short s; } cv; cv.b = v;
    unsigned w = cv.s;
    asm volatile("global_store_short %0, %1, off sc0 sc1"
                 :: "v"(p), "v"(w) : "memory");
}

// Flag-vector all-block barrier (r12, proven). flags[i*16], monotonic.
__device__ __forceinline__ void grid_barrier(unsigned* flags, int t, int blk) {
    __syncthreads();   // drains vmcnt: all waves' sc0sc1 h stores ack'd at LLC
    const unsigned tgt = (unsigned)(t + 1);
    if (threadIdx.x < 64) {
        if (threadIdx.x == 0) {
            unsigned* p = &flags[blk * 16];
            asm volatile("global_store_dword %0, %1, off sc0 sc1"
                         :: "v"(p), "v"(tgt) : "memory");
        }
        const int lane = threadIdx.x;
        for (;;) {
            unsigned m0 = __hip_atomic_load(&flags[(lane * 4 + 0) * 16],
                                            __ATOMIC_RELAXED, __HIP_MEMORY_SCOPE_AGENT);
            unsigned m1 = __hip_atomic_load(&flags[(lane * 4 + 1) * 16],
                                            __ATOMIC_RELAXED, __HIP_MEMORY_SCOPE_AGENT);
            unsigned m2 = __hip_atomic_load(&flags[(lane * 4 + 2) * 16],
                                            __ATOMIC_RELAXED, __HIP_MEMORY_SCOPE_AGENT);
            unsigned m3 = __hip_atomic_load(&flags[(lane * 4 + 3) * 16],
                                            __ATOMIC_RELAXED, __HIP_MEMORY_SCOPE_AGENT);
            bool ok = (m0 >= tgt) & (m1 >= tgt) & (m2 >= tgt) & (m3 >= tgt);
            if (__all(ok)) break;
            __builtin_amdgcn_s_sleep(1);
        }
        __builtin_amdgcn_fence(__ATOMIC_ACQUIRE, "agent");   // one inv: h fresh for cached loads
    }
    __syncthreads();
}

__global__ void __launch_bounds__(256, 1)
lstm_fused(const float* __restrict__ xs, const float* __restrict__ Wi,
           const float* __restrict__ Wh, const float* __restrict__ bias,
           const float* __restrict__ Wo, const float* __restrict__ bo,
           float* __restrict__ out, __bf16* __restrict__ hws,
           unsigned* __restrict__ flags)
{
    __shared__ __bf16 Wlds[16][KTOT + 8];   // 49408 B (bf16-rounded weights)
    __shared__ float  gbuf[64][17];         // 4352 B
    __shared__ float  obuf[4][16][17];      // 4352 B   (total 58112 B)

    const int tid = threadIdx.x;
    const int blk = blockIdx.x;       // 0..255
    const int j0  = blk * 4;
    const int ob0 = (blk >> 5) * 8;   // out-proj batch group (8 batches)
    const int oc0 = (blk & 31) * 16;  // out-proj col group (16 cols)

    // Stage resident gate-weight slab (f32 -> bf16)
    for (int idx = tid; idx < 16 * KTOT; idx += 256) {
        int k = idx >> 4, c = idx & 15;
        int gc = (c >> 2) * H_ + j0 + (c & 3);
        float w = (k < IN_) ? Wi[(size_t)k * G4_ + gc]
                            : Wh[(size_t)(k - IN_) * G4_ + gc];
        Wlds[c][k] = (__bf16)w;
    }
    __syncthreads();

    const int lane = tid & 63;
    const int wave = tid >> 6;
    const int c    = lane & 15;
    const int quad = lane >> 4;
    const int rowA = wave * 16 + c;   // batch row for gate A-frags
    const int kq   = quad * 8;

    const float biasv = bias[(c >> 2) * H_ + j0 + (c & 3)];

    // Hoist step-invariant Wo fragments into registers (f32 -> bf16)
    bf8v wof[8];
    #pragma unroll
    for (int kk = 0; kk < 8; ++kk) {
        int kbase = wave * 256 + kk * 32 + kq;
        #pragma unroll
        for (int j = 0; j < 8; ++j)
            wof[kk][j] = (__bf16)Wo[(size_t)(kbase + j) * OUT_ + oc0 + c];
    }

    // recurrent cell state: thread owns (batch = tid>>2, j = j0 + (tid&3))
    float c_reg = 0.f;
    const int bb = tid >> 2;
    const int jo = tid & 3;

    // h ws layout: [buf(2)][part hi/lo][B][H] bf16  (r12 two-plane layout)
    for (int t = 0; t < T_; ++t) {
        asm volatile("" ::: "memory");   // pin all loads below the grid barrier
        const __bf16* hhi_p = hws + (size_t)(t & 1) * (2 * B_ * H_);
        const __bf16* hlo_p = hhi_p + B_ * H_;
        __bf16* hhi_c = hws + (size_t)((t + 1) & 1) * (2 * B_ * H_);
        __bf16* hlo_c = hhi_c + B_ * H_;

        // ---- phase A: gate MFMA for step t ----
        f4v acc0 = {0.f, 0.f, 0.f, 0.f};   // hi-product chain
        f4v acc1 = {0.f, 0.f, 0.f, 0.f};   // lo-product chain

        // deep prefetch: issue 32 h loads (pass 1, ks=0..15) BEFORE the
        // x-loop; vmcnt retires in order, so the x-loop's first wait
        // covers all of them.
        bf8v ha[16], la[16];
        const __bf16* hh = hhi_p + (size_t)rowA * H_ + kq;
        const __bf16* hl = hlo_p + (size_t)rowA * H_ + kq;
        if (t > 0) {
            #pragma unroll
            for (int ks = 0; ks < 16; ++ks) {
                ha[ks] = load16(hh + ks * 32);
                la[ks] = load16(hl + ks * 32);
            }
        }

        const float* xrow = xs + ((size_t)rowA * T_ + t) * IN_ + kq;
        #pragma unroll
        for (int ks = 0; ks < 16; ++ks) {
            f4v v0 = *(const f4v*)(xrow + ks * 32);
            f4v v1 = *(const f4v*)(xrow + ks * 32 + 4);
            bf8v ah, al;
            #pragma unroll
            for (int j = 0; j < 4; ++j) {
                __bf16 h0 = (__bf16)v0[j], h1 = (__bf16)v1[j];
                ah[j] = h0;  ah[4 + j] = h1;
                al[j]     = (__bf16)(v0[j] - (float)h0);
                al[4 + j] = (__bf16)(v1[j] - (float)h1);
            }
            bf8v w = *(const bf8v*)&Wlds[c][ks * 32 + kq];
            acc0 = __builtin_amdgcn_mfma_f32_16x16x32_bf16(ah, w, acc0, 0, 0, 0);
            acc1 = __builtin_amdgcn_mfma_f32_16x16x32_bf16(al, w, acc1, 0, 0, 0);
        }
        if (t > 0) {
            // consume pass 1, refilling each slot with pass 2 (ks+16)
            #pragma unroll
            for (int ks = 0; ks < 16; ++ks) {
                bf8v ah = ha[ks], al = la[ks];
                bf8v w  = *(const bf8v*)&Wlds[c][IN_ + ks * 32 + kq];
                ha[ks] = load16(hh + (ks + 16) * 32);
                la[ks] = load16(hl + (ks + 16) * 32);
                acc0 = __builtin_amdgcn_mfma_f32_16x16x32_bf16(ah, w, acc0, 0, 0, 0);
                acc1 = __builtin_amdgcn_mfma_f32_16x16x32_bf16(al, w, acc1, 0, 0, 0);
            }
            // consume pass 2
            #pragma unroll
            for (int ks = 0; ks < 16; ++ks) {
                bf8v w = *(const bf8v*)&Wlds[c][IN_ + (ks + 16) * 32 + kq];
                acc0 = __builtin_amdgcn_mfma_f32_16x16x32_bf16(ha[ks], w, acc0, 0, 0, 0);
                acc1 = __builtin_amdgcn_mfma_f32_16x16x32_bf16(la[ks], w, acc1, 0, 0, 0);
            }
        }
        f4v acc = acc0 + acc1;
        #pragma unroll
        for (int r = 0; r < 4; ++r)
            gbuf[wave * 16 + quad * 4 + r][c] = acc[r] + biasv;  // C: col=c, row=quad*4+r

        // ---- phase A2: out-proj partial for step t-1 (r12 verbatim) ----
        if (t > 0) {
            f4v oac = {0.f, 0.f, 0.f, 0.f};
            #pragma unroll
            for (int kk = 0; kk < 8; ++kk) {
                int kbase = wave * 256 + kk * 32 + kq;
                bf8v ah = {}, al = {};
                if (c < 8) {   // A rows 8..15 zero (8 batches per tile)
                    ah = *(const bf8v*)&hhi_p[(size_t)(ob0 + c) * H_ + kbase];
                    al = *(const bf8v*)&hlo_p[(size_t)(ob0 + c) * H_ + kbase];
                }
                oac = __builtin_amdgcn_mfma_f32_16x16x32_bf16(ah, wof[kk], oac, 0, 0, 0);
                oac = __builtin_amdgcn_mfma_f32_16x16x32_bf16(al, wof[kk], oac, 0, 0, 0);
            }
            #pragma unroll
            for (int r = 0; r < 4; ++r)
                obuf[wave][quad * 4 + r][c] = oac[r];
        }
        __syncthreads();

        // ---- phase B: elementwise cell update, write h_t (hi+lo planes) ----
        {
            float gi = gbuf[bb][jo];
            float gf = gbuf[bb][4 + jo];
            float gg = gbuf[bb][8 + jo];
            float go = gbuf[bb][12 + jo];
            c_reg = sigm(gf) * c_reg + sigm(gi) * tanh_f(gg);
            float hn = sigm(go) * tanh_f(c_reg);
            __bf16 hh2 = (__bf16)hn;
            store_bf16_wt(&hhi_c[(size_t)bb * H_ + j0 + jo], hh2);
            store_bf16_wt(&hlo_c[(size_t)bb * H_ + j0 + jo], (__bf16)(hn - (float)hh2));
        }
        // ---- phase B2: reduce out-proj partials, store out[:, t-1, :] ----
        if (t > 0 && tid < 128) {
            int m = tid >> 4, cc = tid & 15;
            float v = obuf[0][m][cc] + obuf[1][m][cc] + obuf[2][m][cc] + obuf[3][m][cc]
                    + bo[oc0 + cc];
            out[(((size_t)(ob0 + m)) * T_ + (t - 1)) * OUT_ + oc0 + cc] = v;
        }

        grid_barrier(flags, t, blk);   // publish h_t; guards gbuf/obuf WAR
    }

    // ---- epilogue: out-proj for t = T-1 (r12 verbatim; buffer 0, T even) ----
    {
        const __bf16* hhi_l = hws;
        const __bf16* hlo_l = hws + B_ * H_;
        f4v oac = {0.f, 0.f, 0.f, 0.f};
        #pragma unroll
        for (int kk = 0; kk < 8; ++kk) {
            int kbase = wave * 256 + kk * 32 + kq;
            bf8v ah = {}, al = {};
            if (c < 8) {
                ah = *(const bf8v*)&hhi_l[(size_t)(ob0 + c) * H_ + kbase];
                al = *(const bf8v*)&hlo_l[(size_t)(ob0 + c) * H_ + kbase];
            }
            oac = __builtin_amdgcn_mfma_f32_16x16x32_bf16(ah, wof[kk], oac, 0, 0, 0);
            oac = __builtin_amdgcn_mfma_f32_16x16x32_bf16(al, wof[kk], oac, 0, 0, 0);
        }
        #pragma unroll
        for (int r = 0; r < 4; ++r)
            obuf[wave][quad * 4 + r][c] = oac[r];
        __syncthreads();
        if (tid < 128) {
            int m = tid >> 4, cc = tid & 15;
            float v = obuf[0][m][cc] + obuf[1][m][cc] + obuf[2][m][cc] + obuf[3][m][cc]
                    + bo[oc0 + cc];
            out[(((size_t)(ob0 + m)) * T_ + (T_ - 1)) * OUT_ + oc0 + cc] = v;
        }
    }
}

extern "C" void kernel_launch(void* const* d_in, const int* in_sizes, int n_in,
                              void* d_out, int out_size, void* d_ws, size_t ws_size,
                              hipStream_t stream) {
    const float* xs = (const float*)d_in[0];
    const float* Wi = (const float*)d_in[1];
    const float* Wh = (const float*)d_in[2];
    const float* b  = (const float*)d_in[3];
    const float* Wo = (const float*)d_in[4];
    const float* bo = (const float*)d_in[5];
    float* out = (float*)d_out;

    // ws layout: [0,16K) flag vector (256 x 64B-padded, zeroed);
    //            [64K, +512K) h double-buffer (hi/lo planes, bf16)
    unsigned* flags = (unsigned*)d_ws;         // flags[i*16], i = 0..255
    __bf16*   hws   = (__bf16*)((char*)d_ws + 65536);

    hipMemsetAsync(d_ws, 0, 32768, stream);    // reset flags (graph-capture safe)

    void* args[] = {(void*)&xs, (void*)&Wi, (void*)&Wh, (void*)&b,
                    (void*)&Wo, (void*)&bo, (void*)&out, (void*)&hws,
                    (void*)&flags};
    hipLaunchCooperativeKernel((void*)lstm_fused, dim3(256), dim3(256), args, 0, stream);
}

// Round 8
// 4132.824 us; speedup vs baseline: 1.3795x; 1.3795x over previous
//
#include <hip/hip_runtime.h>
#include <hip/hip_cooperative_groups.h>

// LSTM: B=64, T=256, IN=512, H=1024 (4H=4096), OUT=512. I/O f32.
// Round-18 = r12 VERBATIM (4237us anchor: two-plane h, flag barrier,
// acquire fence, sc0sc1 h stores) + ONE structural change: the x-part
// of step t+1's gate GEMM runs INSIDE the barrier-wait shadow.
//   r17 post-mortem: explicit register staging regressed (compiler
//   re-scheduled at 120 VGPR); r14: more waves null. The untapped
//   resource is the idle poll wait (~2-3us/step). x-MFMA for t+1 has
//   zero dependence on h_t -> moved between flag-arrive and poll.
//   Critical path becomes: h-load -> h-MFMA -> B -> publish -> poll.
//   xacc0/xacc1 (8 VGPR) carry the x partials across the barrier.
// MFMA accumulation order unchanged (x ks=0..15 then h ks=0..31) ->
// bitwise-identical numerics (absmax 7.8e-3).

#define B_   64
#define T_   256
#define IN_  512
#define H_   1024
#define G4_  4096
#define OUT_ 512
#define KTOT 1536   // IN_ + H_

typedef __bf16 bf8v  __attribute__((ext_vector_type(8)));
typedef float  f4v   __attribute__((ext_vector_type(4)));

__device__ __forceinline__ float sigm(float x) { return 1.f / (1.f + __expf(-x)); }
__device__ __forceinline__ float tanh_f(float x) { return 1.f - 2.f / (__expf(2.f * x) + 1.f); }

// Write-through store of one bf16, bypassing L1 (sc0) and L2 (sc1):
// value is visible at the LLC (agent coherence point) when vmcnt retires.
__device__ __forceinline__ void store_bf16_wt(__bf16* p, __bf16 v) {
    union { __bf16 b; unsigned short s; } cv; cv.b = v;
    unsigned w = cv.s;
    asm volatile("global_store_short %0, %1, off sc0 sc1"
                 :: "v"(p), "v"(w) : "memory");
}

// x-part of the gate GEMM for timestep tt: 16 iters of f32->bf16 hi/lo
// split + 2 MFMA, accumulating into xa0/xa1. Order identical to r12.
#define X_PRE(tt, xa0, xa1)                                                   \
    {                                                                         \
        const float* xrow = xs + ((size_t)rowA * T_ + (size_t)(tt)) * IN_ + kq; \
        _Pragma("unroll")                                                     \
        for (int ks = 0; ks < 16; ++ks) {                                     \
            f4v v0 = *(const f4v*)(xrow + ks * 32);                           \
            f4v v1 = *(const f4v*)(xrow + ks * 32 + 4);                       \
            bf8v ah, al;                                                      \
            _Pragma("unroll")                                                 \
            for (int j = 0; j < 4; ++j) {                                     \
                __bf16 h0 = (__bf16)v0[j], h1 = (__bf16)v1[j];                \
                ah[j] = h0;  ah[4 + j] = h1;                                  \
                al[j]     = (__bf16)(v0[j] - (float)h0);                      \
                al[4 + j] = (__bf16)(v1[j] - (float)h1);                      \
            }                                                                 \
            bf8v w = *(const bf8v*)&Wlds[c][ks * 32 + kq];                    \
            xa0 = __builtin_amdgcn_mfma_f32_16x16x32_bf16(ah, w, xa0, 0, 0, 0); \
            xa1 = __builtin_amdgcn_mfma_f32_16x16x32_bf16(al, w, xa1, 0, 0, 0); \
        }                                                                     \
    }

__global__ void __launch_bounds__(256, 1)
lstm_fused(const float* __restrict__ xs, const float* __restrict__ Wi,
           const float* __restrict__ Wh, const float* __restrict__ bias,
           const float* __restrict__ Wo, const float* __restrict__ bo,
           float* __restrict__ out, __bf16* __restrict__ hws,
           unsigned* __restrict__ flags)
{
    __shared__ __bf16 Wlds[16][KTOT + 8];   // 49408 B (bf16-rounded weights)
    __shared__ float  gbuf[64][17];         // 4352 B
    __shared__ float  obuf[4][16][17];      // 4352 B   (total 58112 B)

    const int tid = threadIdx.x;
    const int blk = blockIdx.x;       // 0..255
    const int j0  = blk * 4;
    const int ob0 = (blk >> 5) * 8;   // out-proj batch group (8 batches)
    const int oc0 = (blk & 31) * 16;  // out-proj col group (16 cols)

    // Stage resident gate-weight slab (f32 -> bf16)
    for (int idx = tid; idx < 16 * KTOT; idx += 256) {
        int k = idx >> 4, c = idx & 15;
        int gc = (c >> 2) * H_ + j0 + (c & 3);
        float w = (k < IN_) ? Wi[(size_t)k * G4_ + gc]
                            : Wh[(size_t)(k - IN_) * G4_ + gc];
        Wlds[c][k] = (__bf16)w;
    }
    __syncthreads();

    const int lane = tid & 63;
    const int wave = tid >> 6;
    const int c    = lane & 15;
    const int quad = lane >> 4;
    const int rowA = wave * 16 + c;   // batch row for gate A-frags
    const int kq   = quad * 8;

    const float biasv = bias[(c >> 2) * H_ + j0 + (c & 3)];

    // Hoist step-invariant Wo fragments into registers (f32 -> bf16)
    bf8v wof[8];
    #pragma unroll
    for (int kk = 0; kk < 8; ++kk) {
        int kbase = wave * 256 + kk * 32 + kq;
        #pragma unroll
        for (int j = 0; j < 8; ++j)
            wof[kk][j] = (__bf16)Wo[(size_t)(kbase + j) * OUT_ + oc0 + c];
    }

    // recurrent cell state: thread owns (batch = tid>>2, j = j0 + (tid&3))
    float c_reg = 0.f;
    const int bb = tid >> 2;
    const int jo = tid & 3;

    // x partial accumulators for the upcoming step (prologue: t=0)
    f4v xacc0 = {0.f, 0.f, 0.f, 0.f};
    f4v xacc1 = {0.f, 0.f, 0.f, 0.f};
    X_PRE(0, xacc0, xacc1);

    // h ws layout: [buf(2)][part hi/lo][B][H] bf16
    for (int t = 0; t < T_; ++t) {
        const __bf16* hhi_p = hws + (size_t)(t & 1) * (2 * B_ * H_);
        const __bf16* hlo_p = hhi_p + B_ * H_;
        __bf16* hhi_c = hws + (size_t)((t + 1) & 1) * (2 * B_ * H_);
        __bf16* hlo_c = hhi_c + B_ * H_;

        // ---- phase A: gate MFMA for step t (x part precomputed) ----
        f4v acc0 = xacc0;   // hi-product chain
        f4v acc1 = xacc1;   // lo-product chain
        if (t > 0) {
            const __bf16* hh = hhi_p + (size_t)rowA * H_ + kq;
            const __bf16* hl = hlo_p + (size_t)rowA * H_ + kq;
            #pragma unroll
            for (int ks = 0; ks < 32; ++ks) {
                bf8v ah = *(const bf8v*)(hh + ks * 32);
                bf8v al = *(const bf8v*)(hl + ks * 32);
                bf8v w  = *(const bf8v*)&Wlds[c][IN_ + ks * 32 + kq];
                acc0 = __builtin_amdgcn_mfma_f32_16x16x32_bf16(ah, w, acc0, 0, 0, 0);
                acc1 = __builtin_amdgcn_mfma_f32_16x16x32_bf16(al, w, acc1, 0, 0, 0);
            }
        }
        f4v acc = acc0 + acc1;
        #pragma unroll
        for (int r = 0; r < 4; ++r)
            gbuf[wave * 16 + quad * 4 + r][c] = acc[r] + biasv;  // C: col=c, row=quad*4+r

        // ---- phase A2: out-proj partial for step t-1 (reads same h_{t-1}) ----
        if (t > 0) {
            f4v oac = {0.f, 0.f, 0.f, 0.f};
            #pragma unroll
            for (int kk = 0; kk < 8; ++kk) {
                int kbase = wave * 256 + kk * 32 + kq;
                bf8v ah = {}, al = {};
                if (c < 8) {   // A rows 8..15 zero (8 batches per tile)
                    ah = *(const bf8v*)&hhi_p[(size_t)(ob0 + c) * H_ + kbase];
                    al = *(const bf8v*)&hlo_p[(size_t)(ob0 + c) * H_ + kbase];
                }
                oac = __builtin_amdgcn_mfma_f32_16x16x32_bf16(ah, wof[kk], oac, 0, 0, 0);
                oac = __builtin_amdgcn_mfma_f32_16x16x32_bf16(al, wof[kk], oac, 0, 0, 0);
            }
            #pragma unroll
            for (int r = 0; r < 4; ++r)
                obuf[wave][quad * 4 + r][c] = oac[r];
        }
        __syncthreads();

        // ---- phase B: elementwise cell update, write h_t (hi+lo, write-through) ----
        {
            float gi = gbuf[bb][jo];
            float gf = gbuf[bb][4 + jo];
            float gg = gbuf[bb][8 + jo];
            float go = gbuf[bb][12 + jo];
            c_reg = sigm(gf) * c_reg + sigm(gi) * tanh_f(gg);
            float hn = sigm(go) * tanh_f(c_reg);
            __bf16 hh = (__bf16)hn;
            store_bf16_wt(&hhi_c[(size_t)bb * H_ + j0 + jo], hh);
            store_bf16_wt(&hlo_c[(size_t)bb * H_ + j0 + jo], (__bf16)(hn - (float)hh));
        }
        // ---- phase B2: reduce out-proj partials, store out[:, t-1, :] ----
        if (t > 0 && tid < 128) {
            int m = tid >> 4, cc = tid & 15;
            float v = obuf[0][m][cc] + obuf[1][m][cc] + obuf[2][m][cc] + obuf[3][m][cc]
                    + bo[oc0 + cc];
            out[(((size_t)(ob0 + m)) * T_ + (t - 1)) * OUT_ + oc0 + cc] = v;
        }

        // ==== grid barrier with x-pre in the wait shadow ====
        __syncthreads();   // drains vmcnt: all waves' sc0sc1 h stores ack'd at LLC
        const unsigned tgt = (unsigned)(t + 1);
        if (tid == 0) {
            unsigned* p = &flags[blk * 16];
            asm volatile("global_store_dword %0, %1, off sc0 sc1"
                         :: "v"(p), "v"(tgt) : "memory");
        }
        // ---- shadow: x-part of step t+1 (no dependence on h_t) ----
        xacc0 = (f4v){0.f, 0.f, 0.f, 0.f};
        xacc1 = (f4v){0.f, 0.f, 0.f, 0.f};
        if (t + 1 < T_) {
            X_PRE(t + 1, xacc0, xacc1);
        }
        asm volatile("" ::: "memory");   // pin x loads above the poll
        // ---- wait ----
        if (tid < 64) {
            const int lane2 = tid;
            for (;;) {
                unsigned m0 = __hip_atomic_load(&flags[(lane2 * 4 + 0) * 16],
                                                __ATOMIC_RELAXED, __HIP_MEMORY_SCOPE_AGENT);
                unsigned m1 = __hip_atomic_load(&flags[(lane2 * 4 + 1) * 16],
                                                __ATOMIC_RELAXED, __HIP_MEMORY_SCOPE_AGENT);
                unsigned m2 = __hip_atomic_load(&flags[(lane2 * 4 + 2) * 16],
                                                __ATOMIC_RELAXED, __HIP_MEMORY_SCOPE_AGENT);
                unsigned m3 = __hip_atomic_load(&flags[(lane2 * 4 + 3) * 16],
                                                __ATOMIC_RELAXED, __HIP_MEMORY_SCOPE_AGENT);
                bool ok = (m0 >= tgt) & (m1 >= tgt) & (m2 >= tgt) & (m3 >= tgt);
                if (__all(ok)) break;
                __builtin_amdgcn_s_sleep(1);
            }
            __builtin_amdgcn_fence(__ATOMIC_ACQUIRE, "agent");   // one inv: h fresh
        }
        __syncthreads();
    }

    // ---- epilogue: out-proj for t = T-1 (h_{T-1} is in buffer 0; T even) ----
    {
        const __bf16* hhi_l = hws;
        const __bf16* hlo_l = hws + B_ * H_;
        f4v oac = {0.f, 0.f, 0.f, 0.f};
        #pragma unroll
        for (int kk = 0; kk < 8; ++kk) {
            int kbase = wave * 256 + kk * 32 + kq;
            bf8v ah = {}, al = {};
            if (c < 8) {
                ah = *(const bf8v*)&hhi_l[(size_t)(ob0 + c) * H_ + kbase];
                al = *(const bf8v*)&hlo_l[(size_t)(ob0 + c) * H_ + kbase];
            }
            oac = __builtin_amdgcn_mfma_f32_16x16x32_bf16(ah, wof[kk], oac, 0, 0, 0);
            oac = __builtin_amdgcn_mfma_f32_16x16x32_bf16(al, wof[kk], oac, 0, 0, 0);
        }
        #pragma unroll
        for (int r = 0; r < 4; ++r)
            obuf[wave][quad * 4 + r][c] = oac[r];
        __syncthreads();
        if (tid < 128) {
            int m = tid >> 4, cc = tid & 15;
            float v = obuf[0][m][cc] + obuf[1][m][cc] + obuf[2][m][cc] + obuf[3][m][cc]
                    + bo[oc0 + cc];
            out[(((size_t)(ob0 + m)) * T_ + (T_ - 1)) * OUT_ + oc0 + cc] = v;
        }
    }
}

extern "C" void kernel_launch(void* const* d_in, const int* in_sizes, int n_in,
                              void* d_out, int out_size, void* d_ws, size_t ws_size,
                              hipStream_t stream) {
    const float* xs = (const float*)d_in[0];
    const float* Wi = (const float*)d_in[1];
    const float* Wh = (const float*)d_in[2];
    const float* b  = (const float*)d_in[3];
    const float* Wo = (const float*)d_in[4];
    const float* bo = (const float*)d_in[5];
    float* out = (float*)d_out;

    // ws layout: [0,16K) flag vector (256 x 64B-padded, zeroed);
    //            [64K, +512K) h double-buffer (hi/lo planes, bf16)
    unsigned* flags = (unsigned*)d_ws;         // flags[i*16], i = 0..255
    __bf16*   hws   = (__bf16*)((char*)d_ws + 65536);

    hipMemsetAsync(d_ws, 0, 32768, stream);    // reset flags (graph-capture safe)

    void* args[] = {(void*)&xs, (void*)&Wi, (void*)&Wh, (void*)&b,
                    (void*)&Wo, (void*)&bo, (void*)&out, (void*)&hws,
                    (void*)&flags};
    hipLaunchCooperativeKernel((void*)lstm_fused, dim3(256), dim3(256), args, 0, stream);
}